// Round 1
// baseline (619.454 us; speedup 1.0000x reference)
//
#include <hip/hip_runtime.h>

using u16 = unsigned short;
using u32 = unsigned int;
using u64 = unsigned long long;
typedef short short8 __attribute__((ext_vector_type(8)));
typedef float f32x4 __attribute__((ext_vector_type(4)));

#define GB  16
#define GNV 8192
#define GNC 4096
#define GD  128
#define GE  49152

#define MFMA __builtin_amdgcn_mfma_f32_16x16x32_bf16

// ---------- helpers ----------

__device__ __forceinline__ u16 f2bf(float f){
    u32 u = __builtin_bit_cast(u32, f);
    u32 r = (u >> 16) & 1u;
    u += 0x7fffu + r;            // round-to-nearest-even
    return (u16)(u >> 16);
}

__device__ __forceinline__ float sigmoidf_(float x){
    return __fdividef(1.f, 1.f + __expf(-x));
}

__device__ __forceinline__ float tanhf_fast(float x){
    float xc = fminf(15.f, fmaxf(-15.f, x));
    float t  = __expf(2.f * xc);
    return __fdividef(t - 1.f, t + 1.f);
}

// LDS tiles are [rows][256B] (128 bf16 per row). XOR-swizzle byte offset with
// (row&7)<<4 so ds_read_b128 column-slices hit 8 distinct 16B bank groups
// (otherwise D=128 row-major is the 32-way-conflict case, guide §G4).
__device__ __forceinline__ char* swzp(const void* base, int row, int bc){
    return (char*)base + row * 256 + (bc ^ ((row & 7) << 4));
}

// A/B fragment for mfma_f32_16x16x32_bf16: lane&15 = row(A)/col(B),
// k = (lane>>4)*8 + e  (8 contiguous bf16 = one 16B read).
__device__ __forceinline__ short8 ldfrag(const u16* tile, int row, int lane, int ks){
    int bc = ks * 64 + ((lane >> 4) << 4);
    return *(const short8*)swzp(tile, row, bc);
}

// stage 16 rows x 128 bf16 from global (bf16) into swizzled LDS tile
__device__ __forceinline__ void stage_bf(u16* tile, const u16* src, int lane){
    const u64* s = (const u64*)src;
    #pragma unroll
    for (int i = lane; i < 512; i += 64)
        *(u64*)swzp(tile, i >> 5, (i & 31) << 3) = s[i];
}

// stage 16 rows x 128 f32 from global, convert to bf16, into swizzled LDS tile
__device__ __forceinline__ void stage_f32(u16* tile, const float* src, int lane){
    const float4* s = (const float4*)src;
    #pragma unroll
    for (int i = lane; i < 512; i += 64){
        float4 v = s[i];
        u64 p = (u64)f2bf(v.x) | ((u64)f2bf(v.y) << 16)
              | ((u64)f2bf(v.z) << 32) | ((u64)f2bf(v.w) << 48);
        *(u64*)swzp(tile, i >> 5, (i & 31) << 3) = p;
    }
}

// ---------- CSR build ----------

__global__ void k_hist(const int* __restrict__ ec, const int* __restrict__ ev,
                       int* cc, int* cv){
    int e = blockIdx.x * 256 + threadIdx.x;
    if (e < GE){ atomicAdd(&cc[ec[e]], 1); atomicAdd(&cv[ev[e]], 1); }
}

__global__ __launch_bounds__(1024) void k_scan(const int* __restrict__ cnt, int* off, int n){
    __shared__ int part[1024];
    int tid = threadIdx.x;
    int chunk = n >> 10;
    int base = tid * chunk;
    int s = 0;
    for (int i = 0; i < chunk; ++i) s += cnt[base + i];
    part[tid] = s;
    __syncthreads();
    #pragma unroll
    for (int ofs = 1; ofs < 1024; ofs <<= 1){
        int v = (tid >= ofs) ? part[tid - ofs] : 0;
        __syncthreads();
        part[tid] += v;
        __syncthreads();
    }
    if (tid == 1023) off[n] = part[1023];
    int run = part[tid] - s;            // exclusive prefix of this chunk
    for (int i = 0; i < chunk; ++i){ off[base + i] = run; run += cnt[base + i]; }
}

__global__ void k_fill(const int* __restrict__ ec, const int* __restrict__ ev,
                       int* cur_c, int* lst_c, int* cur_v, int* lst_v){
    int e = blockIdx.x * 256 + threadIdx.x;
    if (e < GE){
        int c = ec[e], v = ev[e];
        lst_c[atomicAdd(&cur_c[c], 1)] = v;
        lst_v[atomicAdd(&cur_v[v], 1)] = c;
    }
}

// sort each adjacency list -> deterministic accumulation order across replays
__global__ void k_sort(const int* __restrict__ off, int* lst, int n){
    int i = blockIdx.x * 256 + threadIdx.x;
    if (i >= n) return;
    int s = off[i], e = off[i + 1];
    for (int a = s + 1; a < e; ++a){
        int v = lst[a]; int b = a - 1;
        while (b >= s && lst[b] > v){ lst[b + 1] = lst[b]; --b; }
        lst[b + 1] = v;
    }
}

__global__ void k_cvt(const float* __restrict__ s, u16* d, int n){
    int i = blockIdx.x * 256 + threadIdx.x;
    if (i < n) d[i] = f2bf(s[i]);
}

// ---------- spmm: gather rows of src at lst[], sum, write bf16 ----------

__global__ __launch_bounds__(128) void k_spmm(const float* __restrict__ src,
                                              const int* __restrict__ off,
                                              const int* __restrict__ lst,
                                              u16* __restrict__ dst,
                                              int ndst, int nsrc){
    const int node = blockIdx.x, b = blockIdx.y, d = threadIdx.x;
    const float* base = src + (size_t)b * nsrc * GD + d;
    float acc = 0.f;
    int s = off[node], e = off[node + 1];
    for (int a = s; a < e; ++a) acc += base[(size_t)lst[a] * GD];
    dst[((size_t)b * ndst + node) * GD + d] = f2bf(acc);
}

// ---------- fused msg net: Y = gelu(X@W1^T+b1)@W2^T + b2 (in place, bf16) ----------

__global__ __launch_bounds__(256) void k_msg(u16* __restrict__ X,
                                             const u16* __restrict__ W1, const float* __restrict__ b1,
                                             const u16* __restrict__ W2, const float* __restrict__ b2){
    __shared__ __align__(16) u16 Wbuf[128 * 128];   // 32KB: W1 then W2
    __shared__ __align__(16) u16 Xs[4][2048];       // 16KB
    __shared__ __align__(16) u16 Gs[4][2048];       // 16KB
    const int tid = threadIdx.x, lane = tid & 63, w = tid >> 6;
    const size_t row0 = (size_t)blockIdx.x * 64 + w * 16;
    const int l15 = lane & 15, rg = lane >> 4;

    {   const u64* s = (const u64*)W1;
        for (int i = tid; i < 4096; i += 256)
            *(u64*)swzp(Wbuf, i >> 5, (i & 31) << 3) = s[i];
    }
    stage_bf(Xs[w], X + row0 * GD, lane);
    __syncthreads();

    f32x4 acc[8];
    #pragma unroll
    for (int t = 0; t < 8; ++t) acc[t] = f32x4{0.f, 0.f, 0.f, 0.f};
    #pragma unroll
    for (int ks = 0; ks < 4; ++ks){
        short8 a = ldfrag(Xs[w], l15, lane, ks);
        #pragma unroll
        for (int t = 0; t < 8; ++t){
            short8 bfr = ldfrag(Wbuf, t * 16 + l15, lane, ks);
            acc[t] = MFMA(a, bfr, acc[t], 0, 0, 0);
        }
    }
    #pragma unroll
    for (int t = 0; t < 8; ++t){
        int j = t * 16 + l15;
        float bb = b1[j];
        #pragma unroll
        for (int i = 0; i < 4; ++i){
            float v = acc[t][i] + bb;
            float g = 0.5f * v * (1.f + erff(v * 0.70710678f));   // exact gelu
            *(u16*)swzp(Gs[w], rg * 4 + i, j * 2) = f2bf(g);
        }
    }
    __syncthreads();
    {   const u64* s = (const u64*)W2;
        for (int i = tid; i < 4096; i += 256)
            *(u64*)swzp(Wbuf, i >> 5, (i & 31) << 3) = s[i];
    }
    __syncthreads();

    #pragma unroll
    for (int t = 0; t < 8; ++t) acc[t] = f32x4{0.f, 0.f, 0.f, 0.f};
    #pragma unroll
    for (int ks = 0; ks < 4; ++ks){
        short8 a = ldfrag(Gs[w], l15, lane, ks);
        #pragma unroll
        for (int t = 0; t < 8; ++t){
            short8 bfr = ldfrag(Wbuf, t * 16 + l15, lane, ks);
            acc[t] = MFMA(a, bfr, acc[t], 0, 0, 0);
        }
    }
    #pragma unroll
    for (int t = 0; t < 8; ++t){
        int j = t * 16 + l15;
        float bb = b2[j];
        #pragma unroll
        for (int i = 0; i < 4; ++i)
            X[(row0 + rg * 4 + i) * GD + j] = f2bf(acc[t][i] + bb);
    }
}

// ---------- fused GRU cell: Out = GRU(x=Xb, h=Hf) (f32 out) ----------

__global__ __launch_bounds__(256) void k_gru(const u16* __restrict__ Xb, const float* __restrict__ Hf,
                                             const u16* __restrict__ Wih, const float* __restrict__ bih,
                                             const u16* __restrict__ Whh, const float* __restrict__ bhh,
                                             float* __restrict__ Out){
    __shared__ __align__(16) u16 Wsh[6][2048];   // 24KB: ih r,z,n then hh r,z,n (16-col tile)
    __shared__ __align__(16) u16 Xs[4][2048];    // 16KB
    __shared__ __align__(16) u16 Hs[4][2048];    // 16KB
    const int tid = threadIdx.x, lane = tid & 63, w = tid >> 6;
    const size_t row0 = (size_t)blockIdx.x * 64 + w * 16;
    const int l15 = lane & 15, rg = lane >> 4;

    stage_bf (Xs[w], Xb + row0 * GD, lane);
    stage_f32(Hs[w], Hf + row0 * GD, lane);

    for (int jt = 0; jt < 8; ++jt){
        __syncthreads();   // prev iter's frag reads done (iter 0: Xs/Hs visible)
        for (int i = tid; i < 3072; i += 256){
            int blk = i >> 9, within = i & 511;
            int rl = within >> 5, bc = (within & 31) << 3;
            const u16* src = (blk < 3) ? Wih : Whh;
            int gate = (blk < 3) ? blk : blk - 3;
            const u64* srow = (const u64*)(src + (size_t)(gate * 128 + jt * 16 + rl) * GD);
            *(u64*)swzp(Wsh[blk], rl, bc) = srow[bc >> 3];
        }
        __syncthreads();

        f32x4 ar = {0,0,0,0}, az = {0,0,0,0}, an = {0,0,0,0}, hn = {0,0,0,0};
        #pragma unroll
        for (int ks = 0; ks < 4; ++ks){
            short8 a = ldfrag(Xs[w], l15, lane, ks);
            short8 h = ldfrag(Hs[w], l15, lane, ks);
            ar = MFMA(a, ldfrag(Wsh[0], l15, lane, ks), ar, 0, 0, 0);
            az = MFMA(a, ldfrag(Wsh[1], l15, lane, ks), az, 0, 0, 0);
            an = MFMA(a, ldfrag(Wsh[2], l15, lane, ks), an, 0, 0, 0);
            ar = MFMA(h, ldfrag(Wsh[3], l15, lane, ks), ar, 0, 0, 0);
            az = MFMA(h, ldfrag(Wsh[4], l15, lane, ks), az, 0, 0, 0);
            hn = MFMA(h, ldfrag(Wsh[5], l15, lane, ks), hn, 0, 0, 0);
        }
        int j = jt * 16 + l15;
        float bir = bih[j]        + bhh[j];
        float biz = bih[128 + j]  + bhh[128 + j];
        float bin = bih[256 + j];
        float bhn = bhh[256 + j];
        #pragma unroll
        for (int i = 0; i < 4; ++i){
            size_t row = row0 + rg * 4 + i;
            float rr = sigmoidf_(ar[i] + bir);
            float zz = sigmoidf_(az[i] + biz);
            float nn = tanhf_fast(an[i] + bin + rr * (hn[i] + bhn));
            float h0 = Hf[row * GD + j];
            Out[row * GD + j] = (1.f - zz) * nn + zz * h0;
        }
    }
}

// ---------- launch ----------

extern "C" void kernel_launch(void* const* d_in, const int* in_sizes, int n_in,
                              void* d_out, int out_size, void* d_ws, size_t ws_size,
                              hipStream_t stream){
    const float* v_feats  = (const float*)d_in[0];
    const float* c_feats  = (const float*)d_in[1];
    const int*   edge_chk = (const int*)d_in[2];
    const int*   edge_var = (const int*)d_in[3];
    const float* msg_w1   = (const float*)d_in[4];
    const float* msg_b1   = (const float*)d_in[5];
    const float* msg_w2   = (const float*)d_in[6];
    const float* msg_b2   = (const float*)d_in[7];
    const float* var_w_ih = (const float*)d_in[8];
    const float* var_w_hh = (const float*)d_in[9];
    const float* var_b_ih = (const float*)d_in[10];
    const float* var_b_hh = (const float*)d_in[11];
    const float* chk_w_ih = (const float*)d_in[12];
    const float* chk_w_hh = (const float*)d_in[13];
    const float* chk_b_ih = (const float*)d_in[14];
    const float* chk_b_hh = (const float*)d_in[15];

    float* out_v = (float*)d_out;
    float* out_c = out_v + (size_t)GB * GNV * GD;

    char* p = (char*)d_ws;
    auto take = [&](size_t bytes) -> void* {
        void* r = (void*)p; p += (bytes + 255) & ~(size_t)255; return r;
    };
    int* cnt_c = (int*)take(GNC * 4);
    int* cnt_v = (int*)take(GNV * 4);
    int* off_c = (int*)take((GNC + 1) * 4);
    int* off_v = (int*)take((GNV + 1) * 4);
    int* cur_c = (int*)take(GNC * 4);
    int* cur_v = (int*)take(GNV * 4);
    int* lst_c = (int*)take(GE * 4);
    int* lst_v = (int*)take(GE * 4);
    u16* w1b  = (u16*)take((size_t)GD * GD * 2);
    u16* w2b  = (u16*)take((size_t)GD * GD * 2);
    u16* cihb = (u16*)take((size_t)3 * GD * GD * 2);
    u16* chhb = (u16*)take((size_t)3 * GD * GD * 2);
    u16* vihb = (u16*)take((size_t)3 * GD * GD * 2);
    u16* vhhb = (u16*)take((size_t)3 * GD * GD * 2);
    u16* mc = (u16*)take((size_t)GB * GNC * GD * 2);   // 16.8 MB
    u16* mv = (u16*)take((size_t)GB * GNV * GD * 2);   // 33.6 MB

    hipMemsetAsync(cnt_c, 0, GNC * 4, stream);
    hipMemsetAsync(cnt_v, 0, GNV * 4, stream);
    k_hist<<<(GE + 255) / 256, 256, 0, stream>>>(edge_chk, edge_var, cnt_c, cnt_v);
    k_scan<<<1, 1024, 0, stream>>>(cnt_c, off_c, GNC);
    k_scan<<<1, 1024, 0, stream>>>(cnt_v, off_v, GNV);
    hipMemcpyAsync(cur_c, off_c, GNC * 4, hipMemcpyDeviceToDevice, stream);
    hipMemcpyAsync(cur_v, off_v, GNV * 4, hipMemcpyDeviceToDevice, stream);
    k_fill<<<(GE + 255) / 256, 256, 0, stream>>>(edge_chk, edge_var, cur_c, lst_c, cur_v, lst_v);
    k_sort<<<(GNC + 255) / 256, 256, 0, stream>>>(off_c, lst_c, GNC);
    k_sort<<<(GNV + 255) / 256, 256, 0, stream>>>(off_v, lst_v, GNV);

    k_cvt<<<(GD * GD + 255) / 256, 256, 0, stream>>>(msg_w1, w1b, GD * GD);
    k_cvt<<<(GD * GD + 255) / 256, 256, 0, stream>>>(msg_w2, w2b, GD * GD);
    k_cvt<<<(3 * GD * GD + 255) / 256, 256, 0, stream>>>(chk_w_ih, cihb, 3 * GD * GD);
    k_cvt<<<(3 * GD * GD + 255) / 256, 256, 0, stream>>>(chk_w_hh, chhb, 3 * GD * GD);
    k_cvt<<<(3 * GD * GD + 255) / 256, 256, 0, stream>>>(var_w_ih, vihb, 3 * GD * GD);
    k_cvt<<<(3 * GD * GD + 255) / 256, 256, 0, stream>>>(var_w_hh, vhhb, 3 * GD * GD);

    // v -> c
    k_spmm<<<dim3(GNC, GB), 128, 0, stream>>>(v_feats, off_c, lst_c, mc, GNC, GNV);
    k_msg<<<(GB * GNC) / 64, 256, 0, stream>>>(mc, w1b, msg_b1, w2b, msg_b2);
    k_gru<<<(GB * GNC) / 64, 256, 0, stream>>>(mc, c_feats, cihb, chk_b_ih, chhb, chk_b_hh, out_c);
    // c -> v
    k_spmm<<<dim3(GNV, GB), 128, 0, stream>>>(out_c, off_v, lst_v, mv, GNV, GNC);
    k_msg<<<(GB * GNV) / 64, 256, 0, stream>>>(mv, w1b, msg_b1, w2b, msg_b2);
    k_gru<<<(GB * GNV) / 64, 256, 0, stream>>>(mv, v_feats, vihb, var_b_ih, vhhb, var_b_hh, out_v);
}

// Round 2
// 446.361 us; speedup vs baseline: 1.3878x; 1.3878x over previous
//
#include <hip/hip_runtime.h>

using u16 = unsigned short;
using u32 = unsigned int;
using u64 = unsigned long long;
typedef short short8 __attribute__((ext_vector_type(8)));
typedef float f32x4 __attribute__((ext_vector_type(4)));

#define GB  16
#define GNV 8192
#define GNC 4096
#define GD  128
#define GE  49152

#define MFMA __builtin_amdgcn_mfma_f32_16x16x32_bf16

// ---------- helpers ----------

__device__ __forceinline__ u16 f2bf(float f){
    u32 u = __builtin_bit_cast(u32, f);
    u32 r = (u >> 16) & 1u;
    u += 0x7fffu + r;            // round-to-nearest-even
    return (u16)(u >> 16);
}

__device__ __forceinline__ float sigmoidf_(float x){
    return __fdividef(1.f, 1.f + __expf(-x));
}

__device__ __forceinline__ float tanhf_fast(float x){
    float xc = fminf(15.f, fmaxf(-15.f, x));
    float t  = __expf(2.f * xc);
    return __fdividef(t - 1.f, t + 1.f);
}

// LDS tiles are [rows][256B] (128 bf16 per row). XOR-swizzle byte offset with
// (row&7)<<4 so ds_read_b128 column-slices hit 8 distinct 16B bank groups
// (otherwise D=128 row-major is the 32-way-conflict case, guide §G4).
__device__ __forceinline__ char* swzp(const void* base, int row, int bc){
    return (char*)base + row * 256 + (bc ^ ((row & 7) << 4));
}

// A/B fragment for mfma_f32_16x16x32_bf16: lane&15 = row(A)/col(B),
// k = (lane>>4)*8 + e  (8 contiguous bf16 = one 16B read).
__device__ __forceinline__ short8 ldfrag(const u16* tile, int row, int lane, int ks){
    int bc = ks * 64 + ((lane >> 4) << 4);
    return *(const short8*)swzp(tile, row, bc);
}

// stage 16 rows x 128 bf16 from global (bf16) into swizzled LDS tile
__device__ __forceinline__ void stage_bf(u16* tile, const u16* src, int lane){
    const u64* s = (const u64*)src;
    #pragma unroll
    for (int i = lane; i < 512; i += 64)
        *(u64*)swzp(tile, i >> 5, (i & 31) << 3) = s[i];
}

// ---------- CSR build ----------

__global__ void k_hist(const int* __restrict__ ec, const int* __restrict__ ev,
                       int* cc, int* cv){
    int e = blockIdx.x * 256 + threadIdx.x;
    if (e < GE){ atomicAdd(&cc[ec[e]], 1); atomicAdd(&cv[ev[e]], 1); }
}

__global__ __launch_bounds__(1024) void k_scan(const int* __restrict__ cnt, int* off, int n){
    __shared__ int part[1024];
    int tid = threadIdx.x;
    int chunk = n >> 10;
    int base = tid * chunk;
    int s = 0;
    for (int i = 0; i < chunk; ++i) s += cnt[base + i];
    part[tid] = s;
    __syncthreads();
    #pragma unroll
    for (int ofs = 1; ofs < 1024; ofs <<= 1){
        int v = (tid >= ofs) ? part[tid - ofs] : 0;
        __syncthreads();
        part[tid] += v;
        __syncthreads();
    }
    if (tid == 1023) off[n] = part[1023];
    int run = part[tid] - s;            // exclusive prefix of this chunk
    for (int i = 0; i < chunk; ++i){ off[base + i] = run; run += cnt[base + i]; }
}

__global__ void k_fill(const int* __restrict__ ec, const int* __restrict__ ev,
                       int* cur_c, int* lst_c, int* cur_v, int* lst_v){
    int e = blockIdx.x * 256 + threadIdx.x;
    if (e < GE){
        int c = ec[e], v = ev[e];
        lst_c[atomicAdd(&cur_c[c], 1)] = v;
        lst_v[atomicAdd(&cur_v[v], 1)] = c;
    }
}

// sort each adjacency list -> deterministic accumulation order across replays
__global__ void k_sort(const int* __restrict__ off, int* lst, int n){
    int i = blockIdx.x * 256 + threadIdx.x;
    if (i >= n) return;
    int s = off[i], e = off[i + 1];
    for (int a = s + 1; a < e; ++a){
        int v = lst[a]; int b = a - 1;
        while (b >= s && lst[b] > v){ lst[b + 1] = lst[b]; --b; }
        lst[b + 1] = v;
    }
}

__global__ void k_cvt(const float* __restrict__ s, u16* d, int n){
    int i = blockIdx.x * 256 + threadIdx.x;
    if (i < n) d[i] = f2bf(s[i]);
}

// ---------- spmm: gather rows of src at lst[], sum, write bf16 ----------

__global__ __launch_bounds__(128) void k_spmm(const float* __restrict__ src,
                                              const int* __restrict__ off,
                                              const int* __restrict__ lst,
                                              u16* __restrict__ dst,
                                              int ndst, int nsrc){
    const int node = blockIdx.x, b = blockIdx.y, d = threadIdx.x;
    const float* base = src + (size_t)b * nsrc * GD + d;
    float acc = 0.f;
    int s = off[node], e = off[node + 1];
    for (int a = s; a < e; ++a) acc += base[(size_t)lst[a] * GD];
    dst[((size_t)b * ndst + node) * GD + d] = f2bf(acc);
}

// ---------- fused msg net: Y = gelu(X@W1^T+b1)@W2^T + b2 (in place, bf16) ----------

__global__ __launch_bounds__(256) void k_msg(u16* __restrict__ X,
                                             const u16* __restrict__ W1, const float* __restrict__ b1,
                                             const u16* __restrict__ W2, const float* __restrict__ b2){
    __shared__ __align__(16) u16 Wbuf[128 * 128];   // 32KB: W1 then W2
    __shared__ __align__(16) u16 Xs[4][2048];       // 16KB
    __shared__ __align__(16) u16 Gs[4][2048];       // 16KB
    const int tid = threadIdx.x, lane = tid & 63, w = tid >> 6;
    const size_t row0 = (size_t)blockIdx.x * 64 + w * 16;
    const int l15 = lane & 15, rg = lane >> 4;

    {   const u64* s = (const u64*)W1;
        for (int i = tid; i < 4096; i += 256)
            *(u64*)swzp(Wbuf, i >> 5, (i & 31) << 3) = s[i];
    }
    stage_bf(Xs[w], X + row0 * GD, lane);
    __syncthreads();

    f32x4 acc[8];
    #pragma unroll
    for (int t = 0; t < 8; ++t) acc[t] = f32x4{0.f, 0.f, 0.f, 0.f};
    #pragma unroll
    for (int ks = 0; ks < 4; ++ks){
        short8 a = ldfrag(Xs[w], l15, lane, ks);
        #pragma unroll
        for (int t = 0; t < 8; ++t){
            short8 bfr = ldfrag(Wbuf, t * 16 + l15, lane, ks);
            acc[t] = MFMA(a, bfr, acc[t], 0, 0, 0);
        }
    }
    #pragma unroll
    for (int t = 0; t < 8; ++t){
        int j = t * 16 + l15;
        float bb = b1[j];
        #pragma unroll
        for (int i = 0; i < 4; ++i){
            float v = acc[t][i] + bb;
            float g = 0.5f * v * (1.f + erff(v * 0.70710678f));   // exact gelu
            *(u16*)swzp(Gs[w], rg * 4 + i, j * 2) = f2bf(g);
        }
    }
    __syncthreads();
    {   const u64* s = (const u64*)W2;
        for (int i = tid; i < 4096; i += 256)
            *(u64*)swzp(Wbuf, i >> 5, (i & 31) << 3) = s[i];
    }
    __syncthreads();

    #pragma unroll
    for (int t = 0; t < 8; ++t) acc[t] = f32x4{0.f, 0.f, 0.f, 0.f};
    #pragma unroll
    for (int ks = 0; ks < 4; ++ks){
        short8 a = ldfrag(Gs[w], l15, lane, ks);
        #pragma unroll
        for (int t = 0; t < 8; ++t){
            short8 bfr = ldfrag(Wbuf, t * 16 + l15, lane, ks);
            acc[t] = MFMA(a, bfr, acc[t], 0, 0, 0);
        }
    }
    #pragma unroll
    for (int t = 0; t < 8; ++t){
        int j = t * 16 + l15;
        float bb = b2[j];
        #pragma unroll
        for (int i = 0; i < 4; ++i)
            X[(row0 + rg * 4 + i) * GD + j] = f2bf(acc[t][i] + bb);
    }
}

// ---------- fused GRU cell, persistent register weights ----------
// 512 threads = 8 waves; wave w owns output cols [w*16, w*16+16).
// Weights (6 gate-blocks x 16 cols x K=128) live in registers (24 short8/lane),
// loaded once. Grid-strides 64-row tiles with double-buffered LDS staging:
// X bf16 (swizzled), H bf16 (swizzled, for MFMA), H f32 (linear, exact blend).

__global__ __launch_bounds__(512, 2) void k_gru(const u16* __restrict__ Xb, const float* __restrict__ Hf,
                                                const u16* __restrict__ Wih, const float* __restrict__ bih,
                                                const u16* __restrict__ Whh, const float* __restrict__ bhh,
                                                float* __restrict__ Out, int ntiles){
    __shared__ __align__(16) u16  Xs[2][64 * 128];    // 32KB
    __shared__ __align__(16) u16  Hs[2][64 * 128];    // 32KB
    __shared__ __align__(16) float Hraw[2][64 * 128]; // 64KB
    const int tid = threadIdx.x, lane = tid & 63, w = tid >> 6;
    const int l15 = lane & 15, rg = lane >> 4;
    const int j = w * 16 + l15;            // this lane's output column, fixed

    // register weights: wf[gate 0..2 = ih r/z/n, 3..5 = hh r/z/n][ks]
    short8 wf[6][4];
    #pragma unroll
    for (int g = 0; g < 3; ++g){
        #pragma unroll
        for (int ks = 0; ks < 4; ++ks){
            wf[g][ks]     = *(const short8*)(Wih + (size_t)(g * 128 + j) * 128 + ks * 32 + rg * 8);
            wf[g + 3][ks] = *(const short8*)(Whh + (size_t)(g * 128 + j) * 128 + ks * 32 + rg * 8);
        }
    }
    const float bir = bih[j]       + bhh[j];
    const float biz = bih[128 + j] + bhh[128 + j];
    const float bin = bih[256 + j];
    const float bhn = bhh[256 + j];

    const int nk = ntiles / gridDim.x;     // exact: ntiles multiple of grid
    u64 xr[4]; float4 hr[4];

    // issue tile k's global loads into regs
    auto issue = [&](int t){
        const u64*    xs = (const u64*)   (Xb + (size_t)t * 64 * 128);
        const float4* hs = (const float4*)(Hf + (size_t)t * 64 * 128);
        #pragma unroll
        for (int i = 0; i < 4; ++i){ xr[i] = xs[tid + i * 512]; hr[i] = hs[tid + i * 512]; }
    };

    issue(blockIdx.x);
    for (int k = 0; k < nk; ++k){
        const int buf = k & 1;
        // commit staged regs -> LDS
        #pragma unroll
        for (int i = 0; i < 4; ++i){
            int idx = tid + i * 512;
            int row = idx >> 5, c8 = idx & 31;
            *(u64*)swzp(Xs[buf], row, c8 << 3) = xr[i];
            float4 v = hr[i];
            *(float4*)&Hraw[buf][row * 128 + c8 * 4] = v;
            u64 p = (u64)f2bf(v.x) | ((u64)f2bf(v.y) << 16)
                  | ((u64)f2bf(v.z) << 32) | ((u64)f2bf(v.w) << 48);
            *(u64*)swzp(Hs[buf], row, c8 << 3) = p;
        }
        __syncthreads();
        if (k + 1 < nk) issue(blockIdx.x + (k + 1) * gridDim.x);  // overlap with compute

        const size_t row0 = (size_t)(blockIdx.x + (size_t)k * gridDim.x) * 64;
        #pragma unroll
        for (int sub = 0; sub < 4; ++sub){
            const u16* xt = Xs[buf] + sub * 16 * 128;
            const u16* ht = Hs[buf] + sub * 16 * 128;
            f32x4 ar = {0,0,0,0}, az = {0,0,0,0}, an = {0,0,0,0}, hn = {0,0,0,0};
            #pragma unroll
            for (int ks = 0; ks < 4; ++ks){
                short8 a = ldfrag(xt, l15, lane, ks);
                short8 h = ldfrag(ht, l15, lane, ks);
                ar = MFMA(a, wf[0][ks], ar, 0, 0, 0);
                az = MFMA(a, wf[1][ks], az, 0, 0, 0);
                an = MFMA(a, wf[2][ks], an, 0, 0, 0);
                ar = MFMA(h, wf[3][ks], ar, 0, 0, 0);
                az = MFMA(h, wf[4][ks], az, 0, 0, 0);
                hn = MFMA(h, wf[5][ks], hn, 0, 0, 0);
            }
            #pragma unroll
            for (int i = 0; i < 4; ++i){
                int r = sub * 16 + rg * 4 + i;
                float h0 = Hraw[buf][r * 128 + j];
                float rr = sigmoidf_(ar[i] + bir);
                float zz = sigmoidf_(az[i] + biz);
                float nn = tanhf_fast(an[i] + bin + rr * (hn[i] + bhn));
                Out[(row0 + r) * GD + j] = (1.f - zz) * nn + zz * h0;
            }
        }
        __syncthreads();
    }
}

// ---------- launch ----------

extern "C" void kernel_launch(void* const* d_in, const int* in_sizes, int n_in,
                              void* d_out, int out_size, void* d_ws, size_t ws_size,
                              hipStream_t stream){
    const float* v_feats  = (const float*)d_in[0];
    const float* c_feats  = (const float*)d_in[1];
    const int*   edge_chk = (const int*)d_in[2];
    const int*   edge_var = (const int*)d_in[3];
    const float* msg_w1   = (const float*)d_in[4];
    const float* msg_b1   = (const float*)d_in[5];
    const float* msg_w2   = (const float*)d_in[6];
    const float* msg_b2   = (const float*)d_in[7];
    const float* var_w_ih = (const float*)d_in[8];
    const float* var_w_hh = (const float*)d_in[9];
    const float* var_b_ih = (const float*)d_in[10];
    const float* var_b_hh = (const float*)d_in[11];
    const float* chk_w_ih = (const float*)d_in[12];
    const float* chk_w_hh = (const float*)d_in[13];
    const float* chk_b_ih = (const float*)d_in[14];
    const float* chk_b_hh = (const float*)d_in[15];

    float* out_v = (float*)d_out;
    float* out_c = out_v + (size_t)GB * GNV * GD;

    char* p = (char*)d_ws;
    auto take = [&](size_t bytes) -> void* {
        void* r = (void*)p; p += (bytes + 255) & ~(size_t)255; return r;
    };
    int* cnt_c = (int*)take(GNC * 4);
    int* cnt_v = (int*)take(GNV * 4);
    int* off_c = (int*)take((GNC + 1) * 4);
    int* off_v = (int*)take((GNV + 1) * 4);
    int* cur_c = (int*)take(GNC * 4);
    int* cur_v = (int*)take(GNV * 4);
    int* lst_c = (int*)take(GE * 4);
    int* lst_v = (int*)take(GE * 4);
    u16* w1b  = (u16*)take((size_t)GD * GD * 2);
    u16* w2b  = (u16*)take((size_t)GD * GD * 2);
    u16* cihb = (u16*)take((size_t)3 * GD * GD * 2);
    u16* chhb = (u16*)take((size_t)3 * GD * GD * 2);
    u16* vihb = (u16*)take((size_t)3 * GD * GD * 2);
    u16* vhhb = (u16*)take((size_t)3 * GD * GD * 2);
    u16* mc = (u16*)take((size_t)GB * GNC * GD * 2);   // 16.8 MB
    u16* mv = (u16*)take((size_t)GB * GNV * GD * 2);   // 33.6 MB

    hipMemsetAsync(cnt_c, 0, GNC * 4, stream);
    hipMemsetAsync(cnt_v, 0, GNV * 4, stream);
    k_hist<<<(GE + 255) / 256, 256, 0, stream>>>(edge_chk, edge_var, cnt_c, cnt_v);
    k_scan<<<1, 1024, 0, stream>>>(cnt_c, off_c, GNC);
    k_scan<<<1, 1024, 0, stream>>>(cnt_v, off_v, GNV);
    hipMemcpyAsync(cur_c, off_c, GNC * 4, hipMemcpyDeviceToDevice, stream);
    hipMemcpyAsync(cur_v, off_v, GNV * 4, hipMemcpyDeviceToDevice, stream);
    k_fill<<<(GE + 255) / 256, 256, 0, stream>>>(edge_chk, edge_var, cur_c, lst_c, cur_v, lst_v);
    k_sort<<<(GNC + 255) / 256, 256, 0, stream>>>(off_c, lst_c, GNC);
    k_sort<<<(GNV + 255) / 256, 256, 0, stream>>>(off_v, lst_v, GNV);

    k_cvt<<<(GD * GD + 255) / 256, 256, 0, stream>>>(msg_w1, w1b, GD * GD);
    k_cvt<<<(GD * GD + 255) / 256, 256, 0, stream>>>(msg_w2, w2b, GD * GD);
    k_cvt<<<(3 * GD * GD + 255) / 256, 256, 0, stream>>>(chk_w_ih, cihb, 3 * GD * GD);
    k_cvt<<<(3 * GD * GD + 255) / 256, 256, 0, stream>>>(chk_w_hh, chhb, 3 * GD * GD);
    k_cvt<<<(3 * GD * GD + 255) / 256, 256, 0, stream>>>(var_w_ih, vihb, 3 * GD * GD);
    k_cvt<<<(3 * GD * GD + 255) / 256, 256, 0, stream>>>(var_w_hh, vhhb, 3 * GD * GD);

    // v -> c
    k_spmm<<<dim3(GNC, GB), 128, 0, stream>>>(v_feats, off_c, lst_c, mc, GNC, GNV);
    k_msg<<<(GB * GNC) / 64, 256, 0, stream>>>(mc, w1b, msg_b1, w2b, msg_b2);
    k_gru<<<256, 512, 0, stream>>>(mc, c_feats, cihb, chk_b_ih, chhb, chk_b_hh, out_c, (GB * GNC) / 64);
    // c -> v
    k_spmm<<<dim3(GNV, GB), 128, 0, stream>>>(out_c, off_v, lst_v, mv, GNV, GNC);
    k_msg<<<(GB * GNV) / 64, 256, 0, stream>>>(mv, w1b, msg_b1, w2b, msg_b2);
    k_gru<<<256, 512, 0, stream>>>(mv, v_feats, vihb, var_b_ih, vhhb, var_b_hh, out_v, (GB * GNV) / 64);
}

// Round 3
// 340.548 us; speedup vs baseline: 1.8190x; 1.3107x over previous
//
#include <hip/hip_runtime.h>

using u16 = unsigned short;
using u32 = unsigned int;
using u64 = unsigned long long;
typedef short short8 __attribute__((ext_vector_type(8)));
typedef unsigned short ushort8 __attribute__((ext_vector_type(8)));
typedef float f32x4 __attribute__((ext_vector_type(4)));

#define GB  16
#define GNV 8192
#define GNC 4096
#define GD  128
#define GE  49152

#define MFMA __builtin_amdgcn_mfma_f32_16x16x32_bf16

// ---------- helpers ----------

__device__ __forceinline__ u16 f2bf(float f){
    u32 u = __builtin_bit_cast(u32, f);
    u32 r = (u >> 16) & 1u;
    u += 0x7fffu + r;            // round-to-nearest-even
    return (u16)(u >> 16);
}

__device__ __forceinline__ float bf2f(u16 x){
    return __builtin_bit_cast(float, (u32)x << 16);
}

__device__ __forceinline__ u64 pack4(float a, float b, float c, float d){
    return (u64)f2bf(a) | ((u64)f2bf(b) << 16) | ((u64)f2bf(c) << 32) | ((u64)f2bf(d) << 48);
}

__device__ __forceinline__ float sigmoidf_(float x){
    return __fdividef(1.f, 1.f + __expf(-x));
}

__device__ __forceinline__ float tanhf_fast(float x){
    float xc = fminf(15.f, fmaxf(-15.f, x));
    float t  = __expf(2.f * xc);
    return __fdividef(t - 1.f, t + 1.f);
}

// LDS tiles are [rows][256B] (128 bf16 per row). XOR-swizzle byte offset with
// (row&7)<<4 so ds_read_b128 column-slices hit 8 distinct 16B bank groups
// (otherwise D=128 row-major is the 32-way-conflict case, guide §G4).
__device__ __forceinline__ char* swzp(const void* base, int row, int bc){
    return (char*)base + row * 256 + (bc ^ ((row & 7) << 4));
}

// A/B fragment for mfma_f32_16x16x32_bf16: lane&15 = row(A)/col(B),
// k = (lane>>4)*8 + e  (8 contiguous bf16 = one 16B read).
__device__ __forceinline__ short8 ldfrag(const u16* tile, int row, int lane, int ks){
    int bc = ks * 64 + ((lane >> 4) << 4);
    return *(const short8*)swzp(tile, row, bc);
}

// ---------- CSR build ----------

__global__ void k_hist(const int* __restrict__ ec, const int* __restrict__ ev,
                       int* cc, int* cv){
    int e = blockIdx.x * 256 + threadIdx.x;
    if (e < GE){ atomicAdd(&cc[ec[e]], 1); atomicAdd(&cv[ev[e]], 1); }
}

__global__ __launch_bounds__(1024) void k_scan(const int* __restrict__ cnt, int* off, int n){
    __shared__ int part[1024];
    int tid = threadIdx.x;
    int chunk = n >> 10;
    int base = tid * chunk;
    int s = 0;
    for (int i = 0; i < chunk; ++i) s += cnt[base + i];
    part[tid] = s;
    __syncthreads();
    #pragma unroll
    for (int ofs = 1; ofs < 1024; ofs <<= 1){
        int v = (tid >= ofs) ? part[tid - ofs] : 0;
        __syncthreads();
        part[tid] += v;
        __syncthreads();
    }
    if (tid == 1023) off[n] = part[1023];
    int run = part[tid] - s;            // exclusive prefix of this chunk
    for (int i = 0; i < chunk; ++i){ off[base + i] = run; run += cnt[base + i]; }
}

__global__ void k_fill(const int* __restrict__ ec, const int* __restrict__ ev,
                       int* cur_c, int* lst_c, int* cur_v, int* lst_v){
    int e = blockIdx.x * 256 + threadIdx.x;
    if (e < GE){
        int c = ec[e], v = ev[e];
        lst_c[atomicAdd(&cur_c[c], 1)] = v;
        lst_v[atomicAdd(&cur_v[v], 1)] = c;
    }
}

// sort each adjacency list -> deterministic accumulation order across replays
__global__ void k_sort(const int* __restrict__ off, int* lst, int n){
    int i = blockIdx.x * 256 + threadIdx.x;
    if (i >= n) return;
    int s = off[i], e = off[i + 1];
    for (int a = s + 1; a < e; ++a){
        int v = lst[a]; int b = a - 1;
        while (b >= s && lst[b] > v){ lst[b + 1] = lst[b]; --b; }
        lst[b + 1] = v;
    }
}

__global__ void k_cvt(const float* __restrict__ s, u16* d, int n){
    int i = blockIdx.x * 256 + threadIdx.x;
    if (i < n) d[i] = f2bf(s[i]);
}

// ---------- transpose (B,N,D) f32 -> (N,B,D) bf16 ----------

__global__ __launch_bounds__(256) void k_tr(const float* __restrict__ src,
                                            u16* __restrict__ dstT, int n){
    const int node = blockIdx.x, t = threadIdx.x;
    const int b = t >> 4, d0 = (t & 15) * 8;
    const float4* s = (const float4*)(src + ((size_t)b * n + node) * GD + d0);
    float4 v0 = s[0], v1 = s[1];
    u64* p = (u64*)(dstT + (size_t)node * 2048 + t * 8);
    p[0] = pack4(v0.x, v0.y, v0.z, v0.w);
    p[1] = pack4(v1.x, v1.y, v1.z, v1.w);
}

// ---------- spmm: gather bf16 (N,B,D) chunks, sum in f32, write bf16 (B,N,D) ----------
// block = one dst node; thread t owns (batch b = t>>4, dims d0..d0+7).
// Each edge = one contiguous 4KB chunk = one ushort8 per lane.

__global__ __launch_bounds__(256) void k_spmm(const u16* __restrict__ srcT,
                                              const int* __restrict__ off,
                                              const int* __restrict__ lst,
                                              u16* __restrict__ dst, int ndst){
    const int node = blockIdx.x, t = threadIdx.x;
    const int b = t >> 4, d0 = (t & 15) * 8;
    float acc[8];
    #pragma unroll
    for (int i = 0; i < 8; ++i) acc[i] = 0.f;
    const int s = off[node], e = off[node + 1];
    const u16* base = srcT + t * 8;
    for (int a = s; a < e; ++a){
        ushort8 v = *(const ushort8*)(base + (size_t)lst[a] * 2048);
        #pragma unroll
        for (int i = 0; i < 8; ++i) acc[i] += bf2f(v[i]);
    }
    u64* p = (u64*)(dst + ((size_t)b * ndst + node) * GD + d0);
    p[0] = pack4(acc[0], acc[1], acc[2], acc[3]);
    p[1] = pack4(acc[4], acc[5], acc[6], acc[7]);
}

// ---------- fused msg net, persistent register weights ----------
// Y = gelu(X@W1^T+b1)@W2^T + b2, in place (bf16). 512 thr = 8 waves; wave w
// owns cols [w*16,w*16+16) with W1/W2 slices in regs. Grid-strides 64-row
// tiles: double-buffered X staging, single-buffer swizzled G in LDS.

__global__ __launch_bounds__(512, 2) void k_msg(u16* __restrict__ X,
                                                const u16* __restrict__ W1, const float* __restrict__ b1,
                                                const u16* __restrict__ W2, const float* __restrict__ b2,
                                                int ntiles){
    __shared__ __align__(16) u16 Xs[2][64 * 128];   // 32KB
    __shared__ __align__(16) u16 Gs[64 * 128];      // 16KB
    const int tid = threadIdx.x, lane = tid & 63, w = tid >> 6;
    const int l15 = lane & 15, rg = lane >> 4;
    const int j = w * 16 + l15;

    short8 w1f[4], w2f[4];
    #pragma unroll
    for (int ks = 0; ks < 4; ++ks){
        w1f[ks] = *(const short8*)(W1 + (size_t)j * 128 + ks * 32 + rg * 8);
        w2f[ks] = *(const short8*)(W2 + (size_t)j * 128 + ks * 32 + rg * 8);
    }
    const float bb1 = b1[j], bb2 = b2[j];

    const int nk = ntiles / gridDim.x;
    u64 xr[4];
    auto issue = [&](int tt){
        const u64* xs = (const u64*)(X + (size_t)tt * 64 * 128);
        #pragma unroll
        for (int i = 0; i < 4; ++i) xr[i] = xs[tid + i * 512];
    };

    issue(blockIdx.x);
    for (int k = 0; k < nk; ++k){
        const int buf = k & 1;
        #pragma unroll
        for (int i = 0; i < 4; ++i){
            int idx = tid + i * 512;
            *(u64*)swzp(Xs[buf], idx >> 5, (idx & 31) << 3) = xr[i];
        }
        __syncthreads();
        if (k + 1 < nk) issue(blockIdx.x + (k + 1) * gridDim.x);

        #pragma unroll
        for (int sub = 0; sub < 4; ++sub){          // GEMM1 + gelu -> Gs
            const u16* xt = Xs[buf] + sub * 16 * 128;
            f32x4 acc = {0, 0, 0, 0};
            #pragma unroll
            for (int ks = 0; ks < 4; ++ks)
                acc = MFMA(ldfrag(xt, l15, lane, ks), w1f[ks], acc, 0, 0, 0);
            #pragma unroll
            for (int i = 0; i < 4; ++i){
                float v = acc[i] + bb1;
                float g = 0.5f * v * (1.f + erff(v * 0.70710678f));   // exact gelu
                *(u16*)swzp(Gs, sub * 16 + rg * 4 + i, j * 2) = f2bf(g);
            }
        }
        __syncthreads();

        const size_t row0 = (size_t)(blockIdx.x + (size_t)k * gridDim.x) * 64;
        #pragma unroll
        for (int sub = 0; sub < 4; ++sub){          // GEMM2 -> global (in place)
            const u16* gt = Gs + sub * 16 * 128;
            f32x4 acc = {0, 0, 0, 0};
            #pragma unroll
            for (int ks = 0; ks < 4; ++ks)
                acc = MFMA(ldfrag(gt, l15, lane, ks), w2f[ks], acc, 0, 0, 0);
            #pragma unroll
            for (int i = 0; i < 4; ++i)
                X[(row0 + sub * 16 + rg * 4 + i) * GD + j] = f2bf(acc[i] + bb2);
        }
        // no barrier needed: next Gs/Xs writes are fenced by next iter's B1
    }
}

// ---------- fused GRU cell, persistent register weights ----------
// Optionally also writes OutT: bf16 (N,B,D) transposed copy (for next spmm).

__global__ __launch_bounds__(512, 2) void k_gru(const u16* __restrict__ Xb, const float* __restrict__ Hf,
                                                const u16* __restrict__ Wih, const float* __restrict__ bih,
                                                const u16* __restrict__ Whh, const float* __restrict__ bhh,
                                                float* __restrict__ Out, u16* __restrict__ OutT,
                                                int logN, int ntiles){
    __shared__ __align__(16) u16  Xs[2][64 * 128];    // 32KB
    __shared__ __align__(16) u16  Hs[2][64 * 128];    // 32KB
    __shared__ __align__(16) float Hraw[2][64 * 128]; // 64KB
    const int tid = threadIdx.x, lane = tid & 63, w = tid >> 6;
    const int l15 = lane & 15, rg = lane >> 4;
    const int j = w * 16 + l15;            // this lane's output column, fixed
    const int nmask = (1 << logN) - 1;

    // register weights: wf[gate 0..2 = ih r/z/n, 3..5 = hh r/z/n][ks]
    short8 wf[6][4];
    #pragma unroll
    for (int g = 0; g < 3; ++g){
        #pragma unroll
        for (int ks = 0; ks < 4; ++ks){
            wf[g][ks]     = *(const short8*)(Wih + (size_t)(g * 128 + j) * 128 + ks * 32 + rg * 8);
            wf[g + 3][ks] = *(const short8*)(Whh + (size_t)(g * 128 + j) * 128 + ks * 32 + rg * 8);
        }
    }
    const float bir = bih[j]       + bhh[j];
    const float biz = bih[128 + j] + bhh[128 + j];
    const float bin = bih[256 + j];
    const float bhn = bhh[256 + j];

    const int nk = ntiles / gridDim.x;     // exact: ntiles multiple of grid
    u64 xr[4]; float4 hr[4];

    auto issue = [&](int t){
        const u64*    xs = (const u64*)   (Xb + (size_t)t * 64 * 128);
        const float4* hs = (const float4*)(Hf + (size_t)t * 64 * 128);
        #pragma unroll
        for (int i = 0; i < 4; ++i){ xr[i] = xs[tid + i * 512]; hr[i] = hs[tid + i * 512]; }
    };

    issue(blockIdx.x);
    for (int k = 0; k < nk; ++k){
        const int buf = k & 1;
        #pragma unroll
        for (int i = 0; i < 4; ++i){
            int idx = tid + i * 512;
            int row = idx >> 5, c8 = idx & 31;
            *(u64*)swzp(Xs[buf], row, c8 << 3) = xr[i];
            float4 v = hr[i];
            *(float4*)&Hraw[buf][row * 128 + c8 * 4] = v;
            *(u64*)swzp(Hs[buf], row, c8 << 3) = pack4(v.x, v.y, v.z, v.w);
        }
        __syncthreads();
        if (k + 1 < nk) issue(blockIdx.x + (k + 1) * gridDim.x);  // overlap with compute

        const int row0 = (blockIdx.x + k * gridDim.x) * 64;
        #pragma unroll
        for (int sub = 0; sub < 4; ++sub){
            const u16* xt = Xs[buf] + sub * 16 * 128;
            const u16* ht = Hs[buf] + sub * 16 * 128;
            f32x4 ar = {0,0,0,0}, az = {0,0,0,0}, an = {0,0,0,0}, hn = {0,0,0,0};
            #pragma unroll
            for (int ks = 0; ks < 4; ++ks){
                short8 a = ldfrag(xt, l15, lane, ks);
                short8 h = ldfrag(ht, l15, lane, ks);
                ar = MFMA(a, wf[0][ks], ar, 0, 0, 0);
                az = MFMA(a, wf[1][ks], az, 0, 0, 0);
                an = MFMA(a, wf[2][ks], an, 0, 0, 0);
                ar = MFMA(h, wf[3][ks], ar, 0, 0, 0);
                az = MFMA(h, wf[4][ks], az, 0, 0, 0);
                hn = MFMA(h, wf[5][ks], hn, 0, 0, 0);
            }
            #pragma unroll
            for (int i = 0; i < 4; ++i){
                int r = sub * 16 + rg * 4 + i;
                float h0 = Hraw[buf][r * 128 + j];
                float rr = sigmoidf_(ar[i] + bir);
                float zz = sigmoidf_(az[i] + biz);
                float nn = tanhf_fast(an[i] + bin + rr * (hn[i] + bhn));
                float val = (1.f - zz) * nn + zz * h0;
                int rg_ = row0 + r;
                Out[(size_t)rg_ * GD + j] = val;
                if (OutT){
                    int bidx = rg_ >> logN, node = rg_ & nmask;
                    OutT[(((size_t)node << 4) + bidx) * GD + j] = f2bf(val);
                }
            }
        }
        __syncthreads();
    }
}

// ---------- launch ----------

extern "C" void kernel_launch(void* const* d_in, const int* in_sizes, int n_in,
                              void* d_out, int out_size, void* d_ws, size_t ws_size,
                              hipStream_t stream){
    const float* v_feats  = (const float*)d_in[0];
    const float* c_feats  = (const float*)d_in[1];
    const int*   edge_chk = (const int*)d_in[2];
    const int*   edge_var = (const int*)d_in[3];
    const float* msg_w1   = (const float*)d_in[4];
    const float* msg_b1   = (const float*)d_in[5];
    const float* msg_w2   = (const float*)d_in[6];
    const float* msg_b2   = (const float*)d_in[7];
    const float* var_w_ih = (const float*)d_in[8];
    const float* var_w_hh = (const float*)d_in[9];
    const float* var_b_ih = (const float*)d_in[10];
    const float* var_b_hh = (const float*)d_in[11];
    const float* chk_w_ih = (const float*)d_in[12];
    const float* chk_w_hh = (const float*)d_in[13];
    const float* chk_b_ih = (const float*)d_in[14];
    const float* chk_b_hh = (const float*)d_in[15];

    float* out_v = (float*)d_out;
    float* out_c = out_v + (size_t)GB * GNV * GD;

    char* p = (char*)d_ws;
    auto take = [&](size_t bytes) -> void* {
        void* r = (void*)p; p += (bytes + 255) & ~(size_t)255; return r;
    };
    int* cnt_c = (int*)take(GNC * 4);
    int* cnt_v = (int*)take(GNV * 4);
    int* off_c = (int*)take((GNC + 1) * 4);
    int* off_v = (int*)take((GNV + 1) * 4);
    int* cur_c = (int*)take(GNC * 4);
    int* cur_v = (int*)take(GNV * 4);
    int* lst_c = (int*)take(GE * 4);
    int* lst_v = (int*)take(GE * 4);
    u16* w1b  = (u16*)take((size_t)GD * GD * 2);
    u16* w2b  = (u16*)take((size_t)GD * GD * 2);
    u16* cihb = (u16*)take((size_t)3 * GD * GD * 2);
    u16* chhb = (u16*)take((size_t)3 * GD * GD * 2);
    u16* vihb = (u16*)take((size_t)3 * GD * GD * 2);
    u16* vhhb = (u16*)take((size_t)3 * GD * GD * 2);
    u16* mc = (u16*)take((size_t)GB * GNC * GD * 2);   // 16.8 MB
    u16* mv = (u16*)take((size_t)GB * GNV * GD * 2);   // 33.6 MB
    u16* vT = (u16*)take((size_t)GNV * GB * GD * 2);   // 33.6 MB (NV,B,D) bf16
    u16* cT = (u16*)take((size_t)GNC * GB * GD * 2);   // 16.8 MB (NC,B,D) bf16

    hipMemsetAsync(cnt_c, 0, GNC * 4, stream);
    hipMemsetAsync(cnt_v, 0, GNV * 4, stream);
    k_hist<<<(GE + 255) / 256, 256, 0, stream>>>(edge_chk, edge_var, cnt_c, cnt_v);
    k_scan<<<1, 1024, 0, stream>>>(cnt_c, off_c, GNC);
    k_scan<<<1, 1024, 0, stream>>>(cnt_v, off_v, GNV);
    hipMemcpyAsync(cur_c, off_c, GNC * 4, hipMemcpyDeviceToDevice, stream);
    hipMemcpyAsync(cur_v, off_v, GNV * 4, hipMemcpyDeviceToDevice, stream);
    k_fill<<<(GE + 255) / 256, 256, 0, stream>>>(edge_chk, edge_var, cur_c, lst_c, cur_v, lst_v);
    k_sort<<<(GNC + 255) / 256, 256, 0, stream>>>(off_c, lst_c, GNC);
    k_sort<<<(GNV + 255) / 256, 256, 0, stream>>>(off_v, lst_v, GNV);

    k_cvt<<<(GD * GD + 255) / 256, 256, 0, stream>>>(msg_w1, w1b, GD * GD);
    k_cvt<<<(GD * GD + 255) / 256, 256, 0, stream>>>(msg_w2, w2b, GD * GD);
    k_cvt<<<(3 * GD * GD + 255) / 256, 256, 0, stream>>>(chk_w_ih, cihb, 3 * GD * GD);
    k_cvt<<<(3 * GD * GD + 255) / 256, 256, 0, stream>>>(chk_w_hh, chhb, 3 * GD * GD);
    k_cvt<<<(3 * GD * GD + 255) / 256, 256, 0, stream>>>(var_w_ih, vihb, 3 * GD * GD);
    k_cvt<<<(3 * GD * GD + 255) / 256, 256, 0, stream>>>(var_w_hh, vhhb, 3 * GD * GD);
    k_tr<<<GNV, 256, 0, stream>>>(v_feats, vT, GNV);

    // v -> c
    k_spmm<<<GNC, 256, 0, stream>>>(vT, off_c, lst_c, mc, GNC);
    k_msg<<<256, 512, 0, stream>>>(mc, w1b, msg_b1, w2b, msg_b2, (GB * GNC) / 64);
    k_gru<<<256, 512, 0, stream>>>(mc, c_feats, cihb, chk_b_ih, chhb, chk_b_hh,
                                   out_c, cT, 12, (GB * GNC) / 64);
    // c -> v
    k_spmm<<<GNV, 256, 0, stream>>>(cT, off_v, lst_v, mv, GNV);
    k_msg<<<256, 512, 0, stream>>>(mv, w1b, msg_b1, w2b, msg_b2, (GB * GNV) / 64);
    k_gru<<<256, 512, 0, stream>>>(mv, v_feats, vihb, var_b_ih, vhhb, var_b_hh,
                                   out_v, (u16*)nullptr, 13, (GB * GNV) / 64);
}